// Round 2
// baseline (13951.344 us; speedup 1.0000x reference)
//
#include <hip/hip_runtime.h>
#include <cstddef>

// Model dims
#define BB   4
#define TS   1024
#define DM   1024
#define DFF  4096
#define NHD  16
#define HDM  64
#define NLY  4
#define TOKD 256
#define POSD 768

__device__ __forceinline__ float gelu_f(float x) {
  // JAX default gelu (approximate=True, tanh form)
  float x3 = x * x * x;
  return 0.5f * x * (1.0f + tanhf(0.7978845608028654f * (x + 0.044715f * x3)));
}

// h[b,t,:] = [tok_emb[x_in[b,t]], pos_emb[t]]; x_in = shift-right with BOS=1
__global__ __launch_bounds__(256) void k_embed(const int* __restrict__ x,
    const float* __restrict__ tok, const float* __restrict__ pos,
    float* __restrict__ h) {
  int idx = blockIdx.x * 256 + threadIdx.x;   // over B*T*DM = 4M
  int d  = idx & (DM - 1);
  int bt = idx >> 10;
  int t  = bt & (TS - 1);
  int b  = bt >> 10;
  float v;
  if (d < TOKD) {
    int tk = (t == 0) ? 1 : x[b * TS + t - 1];
    v = tok[tk * TOKD + d];
  } else {
    v = pos[t * POSD + (d - TOKD)];
  }
  h[idx] = v;
}

// One wave per row (1024 dims, 16 elems/lane).
__global__ __launch_bounds__(256) void k_ln(const float* __restrict__ in,
    const float* __restrict__ g, const float* __restrict__ bta,
    float* __restrict__ out) {
  int row  = blockIdx.x * 4 + (threadIdx.x >> 6);
  int lane = threadIdx.x & 63;
  const float* p = in + (size_t)row * DM;
  float vals[16];
  float s = 0.f, s2 = 0.f;
#pragma unroll
  for (int i = 0; i < 16; i++) {
    float v = p[lane + 64 * i];
    vals[i] = v; s += v; s2 += v * v;
  }
#pragma unroll
  for (int off = 32; off; off >>= 1) {
    s  += __shfl_xor(s, off);
    s2 += __shfl_xor(s2, off);
  }
  float mu  = s * (1.f / DM);
  float var = s2 * (1.f / DM) - mu * mu;
  float rs  = rsqrtf(var + 1e-5f);
#pragma unroll
  for (int i = 0; i < 16; i++) {
    int d = lane + 64 * i;
    out[(size_t)row * DM + d] = (vals[i] - mu) * rs * g[d] + bta[d];
  }
}

// C[M,N] = (GELU?)(A[M,K] * Bm[N,K]^T + bias[N]) (+ res[M,N])
// 64x64 C-tile per 256-thread block, 4x4 per thread, K-tile 16.
template <bool GELU>
__global__ __launch_bounds__(256) void k_gemm(const float* __restrict__ A,
    const float* __restrict__ Bm, const float* __restrict__ bias,
    const float* __restrict__ res, float* __restrict__ C,
    int M, int N, int K) {
  __shared__ float As[16][65];
  __shared__ float Bs[16][65];
  int tid = threadIdx.x;
  int tx = tid & 15, ty = tid >> 4;
  int n0 = blockIdx.x * 64, m0 = blockIdx.y * 64;
  int lk = tid & 15, lr = tid >> 4;
  const float* Ap = A  + (size_t)m0 * K + lk;
  const float* Bp = Bm + (size_t)n0 * K + lk;
  float acc[4][4] = {};
  for (int k0 = 0; k0 < K; k0 += 16) {
    __syncthreads();
#pragma unroll
    for (int i = 0; i < 4; i++) {
      As[lk][lr + 16 * i] = Ap[(size_t)(lr + 16 * i) * K + k0];
      Bs[lk][lr + 16 * i] = Bp[(size_t)(lr + 16 * i) * K + k0];
    }
    __syncthreads();
#pragma unroll
    for (int kk = 0; kk < 16; kk++) {
      float av[4], bv[4];
#pragma unroll
      for (int i = 0; i < 4; i++) av[i] = As[kk][ty + 16 * i];
#pragma unroll
      for (int j = 0; j < 4; j++) bv[j] = Bs[kk][tx + 16 * j];
#pragma unroll
      for (int i = 0; i < 4; i++)
#pragma unroll
        for (int j = 0; j < 4; j++)
          acc[i][j] += av[i] * bv[j];
    }
  }
#pragma unroll
  for (int i = 0; i < 4; i++) {
    int m = m0 + ty + 16 * i;
#pragma unroll
    for (int j = 0; j < 4; j++) {
      int n = n0 + tx + 16 * j;
      float v = acc[i][j] + bias[n];
      if (GELU) v = gelu_f(v);
      if (res) v += res[(size_t)m * N + n];
      C[(size_t)m * N + n] = v;
    }
  }
}

// Flash attention for ONE batch element: block = 256 threads handles one
// (head, 64-query tile). qkv is [T, 3*DM] for this batch; output ACCUMULATES
// into hres ([T, DM] slice of the residual stream): hres += attn.
// Thread (r = tid>>2, cg = tid&3) owns query row r, dim group cg (16 wide).
// Online softmax; P tile aliased over dead K tile.
__global__ __launch_bounds__(256) void k_flash(const float* __restrict__ qkv,
                                               float* __restrict__ hres) {
  __shared__ float Qs[64 * 68];
  __shared__ float Ks[64 * 68];   // re-used as P after scores are consumed
  __shared__ float Vs[64 * 68];
  int hh = blockIdx.x;            // 0..15
  int qt = blockIdx.y;            // 0..15
  int tid = threadIdx.x;
  int ld_d = tid & 63, ld_r = tid >> 6;
  const float* base = qkv + hh * HDM;
  // stage Q tile (coalesced), then copy own row to registers
#pragma unroll
  for (int i = 0; i < 16; i++) {
    int rr = ld_r + 4 * i;
    Qs[rr * 68 + ld_d] = base[(size_t)(qt * 64 + rr) * (3 * DM) + ld_d];
  }
  __syncthreads();
  int r = tid >> 2, cg = tid & 3;
  float4 qreg[16];
  {
    const float4* q4 = (const float4*)(Qs + r * 68);
#pragma unroll
    for (int i = 0; i < 16; i++) qreg[i] = q4[i];
  }
  float o[16];
#pragma unroll
  for (int i = 0; i < 16; i++) o[i] = 0.f;
  float m = -1e30f, l = 0.f;

  for (int st = 0; st <= qt; st++) {
    __syncthreads();  // prior tile's PV (Ks-as-P, Vs readers) done
#pragma unroll
    for (int i = 0; i < 16; i++) {
      int rr = ld_r + 4 * i;
      size_t rowoff = (size_t)(st * 64 + rr) * (3 * DM);
      Ks[rr * 68 + ld_d] = base[rowoff + DM + ld_d];
      Vs[rr * 68 + ld_d] = base[rowoff + 2 * DM + ld_d];
    }
    __syncthreads();
    float s[16];
#pragma unroll
    for (int j = 0; j < 16; j++) {
      int col = cg * 16 + j;
      const float4* k4 = (const float4*)(Ks + col * 68);
      float acc = 0.f;
#pragma unroll
      for (int d4 = 0; d4 < 16; d4++) {
        float4 qa = qreg[d4], ka = k4[d4];
        acc += qa.x * ka.x; acc += qa.y * ka.y;
        acc += qa.z * ka.z; acc += qa.w * ka.w;
      }
      s[j] = acc * 0.125f;  // 1/sqrt(64)
    }
    if (st == qt) {
#pragma unroll
      for (int j = 0; j < 16; j++)
        if (cg * 16 + j > r) s[j] = -1e30f;
    }
    float mt = s[0];
#pragma unroll
    for (int j = 1; j < 16; j++) mt = fmaxf(mt, s[j]);
    mt = fmaxf(mt, __shfl_xor(mt, 1));   // 4 colgroups of a row are
    mt = fmaxf(mt, __shfl_xor(mt, 2));   // consecutive lanes
    float mn = fmaxf(m, mt);
    float corr = __expf(m - mn);
    __syncthreads();  // all lanes done reading Ks before P overwrite
    float psum = 0.f;
#pragma unroll
    for (int j = 0; j < 16; j++) {
      float p = __expf(s[j] - mn);
      Ks[r * 68 + cg * 16 + j] = p;
      psum += p;
    }
    psum += __shfl_xor(psum, 1);
    psum += __shfl_xor(psum, 2);
    l = l * corr + psum;
    m = mn;
#pragma unroll
    for (int i = 0; i < 16; i++) o[i] *= corr;
    __syncthreads();  // P visible
    const float* prow = Ks + r * 68;
#pragma unroll 4
    for (int kk = 0; kk < 64; kk++) {
      float p = prow[kk];
      const float4* v4 = (const float4*)(Vs + kk * 68 + cg * 16);
      float4 a0 = v4[0], a1 = v4[1], a2 = v4[2], a3 = v4[3];
      o[0]  += p * a0.x; o[1]  += p * a0.y; o[2]  += p * a0.z; o[3]  += p * a0.w;
      o[4]  += p * a1.x; o[5]  += p * a1.y; o[6]  += p * a1.z; o[7]  += p * a1.w;
      o[8]  += p * a2.x; o[9]  += p * a2.y; o[10] += p * a2.z; o[11] += p * a2.w;
      o[12] += p * a3.x; o[13] += p * a3.y; o[14] += p * a3.z; o[15] += p * a3.w;
    }
  }
  // residual accumulate: hres += attn (disjoint 16-float slice per thread)
  float inv = 1.0f / l;
  float* op = hres + (size_t)(qt * 64 + r) * DM + hh * HDM + cg * 16;
#pragma unroll
  for (int j = 0; j < 16; j++) op[j] += o[j] * inv;
}

// logits (M=2) + log_softmax, one wave per token row
__global__ __launch_bounds__(256) void k_logits(const float* __restrict__ h,
    const float* __restrict__ w, const float* __restrict__ bz,
    float* __restrict__ out) {
  int row  = blockIdx.x * 4 + (threadIdx.x >> 6);
  int lane = threadIdx.x & 63;
  const float* hp = h + (size_t)row * DM;
  float s0 = 0.f, s1 = 0.f;
#pragma unroll
  for (int i = 0; i < 16; i++) {
    float v = hp[lane + 64 * i];
    s0 += v * w[lane + 64 * i];
    s1 += v * w[DM + lane + 64 * i];
  }
#pragma unroll
  for (int off = 32; off; off >>= 1) {
    s0 += __shfl_xor(s0, off);
    s1 += __shfl_xor(s1, off);
  }
  if (lane == 0) {
    float z0 = s0 + bz[0], z1 = s1 + bz[1];
    float mx  = fmaxf(z0, z1);
    float lse = mx + logf(expf(z0 - mx) + expf(z1 - mx));
    out[row * 2]     = z0 - lse;
    out[row * 2 + 1] = z1 - lse;
  }
}

extern "C" void kernel_launch(void* const* d_in, const int* in_sizes, int n_in,
                              void* d_out, int out_size, void* d_ws, size_t ws_size,
                              hipStream_t stream) {
  const int*   x     = (const int*)d_in[0];
  const float* tokE  = (const float*)d_in[1];
  const float* posE  = (const float*)d_in[2];
  const float* w_qkv = (const float*)d_in[3];
  const float* b_qkv = (const float*)d_in[4];
  const float* ln1g  = (const float*)d_in[5];
  const float* ln1b  = (const float*)d_in[6];
  const float* ln2g  = (const float*)d_in[7];
  const float* ln2b  = (const float*)d_in[8];
  const float* fw1   = (const float*)d_in[9];
  const float* fb1   = (const float*)d_in[10];
  const float* fw2   = (const float*)d_in[11];
  const float* fb2   = (const float*)d_in[12];
  const float* outw  = (const float*)d_in[13];
  const float* outb  = (const float*)d_in[14];
  float* out = (float*)d_out;

  const size_t NT = (size_t)BB * TS;  // 4096 tokens
  // Workspace budget: 32 MB total.
  //   h   : NT*DM fp32            = 16 MB (persistent residual stream)
  //   scr : 4M floats             = 16 MB, time-shared:
  //         attention phase (per batch b): a = scr[0 : 1M]   (TS*DM)
  //                                        qkv = scr[1M : 4M] (TS*3*DM)
  //         FF phase (per row chunk c):    f1 = scr[0 : 4M]   (1024*DFF)
  float* ws  = (float*)d_ws;
  float* h   = ws;
  float* scr = h + NT * DM;
  float* a   = scr;
  float* qkv = scr + (size_t)TS * DM;
  float* f1  = scr;

  k_embed<<<(NT * DM) / 256, 256, 0, stream>>>(x, tokE, posE, h);
  for (int l = 0; l < NLY; l++) {
    // --- attention phase, chunked per batch element (scratch: 16 MB) ---
    for (int b = 0; b < BB; b++) {
      float* hb = h + (size_t)b * TS * DM;
      k_ln<<<TS / 4, 256, 0, stream>>>(hb, ln1g + l * DM, ln1b + l * DM, a);
      k_gemm<false><<<dim3(3 * DM / 64, TS / 64), 256, 0, stream>>>(
          a, w_qkv + (size_t)l * 3 * DM * DM, b_qkv + l * 3 * DM, nullptr, qkv,
          TS, 3 * DM, DM);
      k_flash<<<dim3(NHD, TS / 64), 256, 0, stream>>>(qkv, hb);  // hb += attn
    }
    // --- ln2 in place over all tokens ---
    k_ln<<<NT / 4, 256, 0, stream>>>(h, ln2g + l * DM, ln2b + l * DM, h);
    // --- FF phase, chunked over 1024-row groups (scratch: 16 MB) ---
    for (int c = 0; c < 4; c++) {
      float* hc = h + (size_t)c * 1024 * DM;
      k_gemm<true><<<dim3(DFF / 64, 1024 / 64), 256, 0, stream>>>(
          hc, fw1 + (size_t)l * DFF * DM, fb1 + l * DFF, nullptr, f1,
          1024, DFF, DM);
      k_gemm<false><<<dim3(DM / 64, 1024 / 64), 256, 0, stream>>>(
          f1, fw2 + (size_t)l * DM * DFF, fb2 + l * DM, hc, hc,
          1024, DM, DFF);
    }
  }
  k_logits<<<NT / 4, 256, 0, stream>>>(h, outw, outb, out);
}

// Round 4
// 7749.979 us; speedup vs baseline: 1.8002x; 1.8002x over previous
//
#include <hip/hip_runtime.h>
#include <cstddef>
#include <cstdint>

// Model dims
#define BB   4
#define TS   1024
#define DM   1024
#define DFF  4096
#define NHD  16
#define HDM  64
#define NLY  4
#define TOKD 256
#define POSD 768

typedef __bf16 bf16_t;
typedef __bf16 bf16x4 __attribute__((ext_vector_type(4)));
typedef __bf16 bf16x8 __attribute__((ext_vector_type(8)));
typedef float  f32x4  __attribute__((ext_vector_type(4)));

#define GLOAD_LDS16(gp, lp)                                                  \
  __builtin_amdgcn_global_load_lds(                                          \
      (const __attribute__((address_space(1))) void*)(gp),                   \
      (__attribute__((address_space(3))) void*)(lp), 16, 0, 0)

__device__ __forceinline__ float gelu_f(float x) {
  float x3 = x * x * x;
  return 0.5f * x * (1.0f + tanhf(0.7978845608028654f * (x + 0.044715f * x3)));
}

// h[b,t,:] = [tok_emb[x_in[b,t]], pos_emb[t]]; x_in = shift-right with BOS=1
__global__ __launch_bounds__(256) void k_embed(const int* __restrict__ x,
    const float* __restrict__ tok, const float* __restrict__ pos,
    float* __restrict__ h) {
  int idx = blockIdx.x * 256 + threadIdx.x;
  int d  = idx & (DM - 1);
  int bt = idx >> 10;
  int t  = bt & (TS - 1);
  int b  = bt >> 10;
  float v;
  if (d < TOKD) {
    int tk = (t == 0) ? 1 : x[b * TS + t - 1];
    v = tok[tk * TOKD + d];
  } else {
    v = pos[t * POSD + (d - TOKD)];
  }
  h[idx] = v;
}

// fp32 -> bf16 convert. dst is dense [rows, 1<<shift]; src has row stride
// `stride` (elements). One float4 per thread; grid = rows*cols/1024.
__global__ __launch_bounds__(256) void k_cvt(const float* __restrict__ src,
    bf16_t* __restrict__ dst, int stride, int shift) {
  int idx = (blockIdx.x * 256 + threadIdx.x) * 4;
  int r = idx >> shift, c = idx & ((1 << shift) - 1);
  float4 v = *(const float4*)(src + (size_t)r * stride + c);
  bf16x4 o = { (bf16_t)v.x, (bf16_t)v.y, (bf16_t)v.z, (bf16_t)v.w };
  *(bf16x4*)(dst + idx) = o;
}

// One wave per row (1024 dims, 16 elems/lane). Optional fp32 / bf16 outputs.
__global__ __launch_bounds__(256) void k_ln(const float* __restrict__ in,
    const float* __restrict__ g, const float* __restrict__ bta,
    float* __restrict__ out_f, bf16_t* __restrict__ out_bf) {
  int row  = blockIdx.x * 4 + (threadIdx.x >> 6);
  int lane = threadIdx.x & 63;
  const float* p = in + (size_t)row * DM;
  float vals[16];
  float s = 0.f, s2 = 0.f;
#pragma unroll
  for (int i = 0; i < 16; i++) {
    float v = p[lane + 64 * i];
    vals[i] = v; s += v; s2 += v * v;
  }
#pragma unroll
  for (int off = 32; off; off >>= 1) {
    s  += __shfl_xor(s, off);
    s2 += __shfl_xor(s2, off);
  }
  float mu  = s * (1.f / DM);
  float var = s2 * (1.f / DM) - mu * mu;
  float rs  = rsqrtf(var + 1e-5f);
#pragma unroll
  for (int i = 0; i < 16; i++) {
    int d = lane + 64 * i;
    float v = (vals[i] - mu) * rs * g[d] + bta[d];
    if (out_f)  out_f[(size_t)row * DM + d] = v;
    if (out_bf) out_bf[(size_t)row * DM + d] = (bf16_t)v;
  }
}

// MFMA bf16 GEMM: C[M,N] = epi(A[M,K] * B[N,K]^T + bias[N])
// 128x128 C-tile per 256-thread block (4 waves, 2x2 of 64x64), BK=32,
// 16x16x32 MFMA, 4x4 fragments per wave. A,B bf16 via global_load_lds w=16.
// ACC: C[m][n] += v (split-K / residual accumulate).
// Requires M%128==N%128==0, K%32==0, row strides == K (A,B), == N (C).
template <bool GELU, bool ACC, typename CT>
__global__ __launch_bounds__(256) void k_gemm(
    const bf16_t* __restrict__ A, const bf16_t* __restrict__ B,
    const float* __restrict__ bias, CT* __restrict__ C,
    int M, int N, int K) {
  __shared__ __align__(16) bf16_t As[128 * 32];
  __shared__ __align__(16) bf16_t Bs[128 * 32];
  const int tid  = threadIdx.x;
  const int wave = tid >> 6, lane = tid & 63;
  const int m0 = blockIdx.y * 128, n0 = blockIdx.x * 128;
  const int wm = (wave >> 1) * 64, wn = (wave & 1) * 64;
  f32x4 acc[4][4];
#pragma unroll
  for (int i = 0; i < 4; i++)
#pragma unroll
    for (int j = 0; j < 4; j++) acc[i][j] = {0.f, 0.f, 0.f, 0.f};

  // staging: wave owns 16 rows per issue; lane -> row lane>>2, 8 bf16 at
  // (lane&3)*8. LDS dest = wave-uniform base + lane*16 (global_load_lds rule):
  // lane*8 elems = (lane>>2)*32 + (lane&3)*8 -> row-major [16,32] tile.
  const int srow = wave * 16 + (lane >> 2);
  const int scol = (lane & 3) * 8;
  const bf16_t* Ag = A + (size_t)(m0 + srow) * K + scol;
  const bf16_t* Bg = B + (size_t)(n0 + srow) * K + scol;
  bf16_t* AsW = As + wave * 16 * 32;
  bf16_t* BsW = Bs + wave * 16 * 32;
  const int fr = lane & 15, fq = lane >> 4;   // fragment row / quad

  for (int k0 = 0; k0 < K; k0 += 32) {
    __syncthreads();
    GLOAD_LDS16(Ag + k0, AsW);
    GLOAD_LDS16(Ag + (size_t)64 * K + k0, AsW + 64 * 32);
    GLOAD_LDS16(Bg + k0, BsW);
    GLOAD_LDS16(Bg + (size_t)64 * K + k0, BsW + 64 * 32);
    __syncthreads();   // drains vmcnt (global_load_lds)
    bf16x8 af[4], bfv[4];
#pragma unroll
    for (int i = 0; i < 4; i++)
      af[i] = *(const bf16x8*)&As[(wm + i * 16 + fr) * 32 + fq * 8];
#pragma unroll
    for (int j = 0; j < 4; j++)
      bfv[j] = *(const bf16x8*)&Bs[(wn + j * 16 + fr) * 32 + fq * 8];
#pragma unroll
    for (int i = 0; i < 4; i++)
#pragma unroll
      for (int j = 0; j < 4; j++)
        acc[i][j] = __builtin_amdgcn_mfma_f32_16x16x32_bf16(
            af[i], bfv[j], acc[i][j], 0, 0, 0);
  }
  // epilogue: C/D layout col = lane&15, row = (lane>>4)*4 + reg  [m89]
#pragma unroll
  for (int i = 0; i < 4; i++) {
#pragma unroll
    for (int j = 0; j < 4; j++) {
#pragma unroll
      for (int r = 0; r < 4; r++) {
        int m = m0 + wm + i * 16 + fq * 4 + r;
        int n = n0 + wn + j * 16 + fr;
        float v = acc[i][j][r];
        if (bias) v += bias[n];
        if (GELU) v = gelu_f(v);
        size_t off = (size_t)m * N + n;
        if (ACC) C[off] = (CT)((float)C[off] + v);
        else     C[off] = (CT)v;
      }
    }
  }
}

// Flash attention, one batch element; qkv bf16 [T, 3*DM]; hres += attn (fp32).
// Block 256 = one (head, 64-query tile). Thread (r=tid>>2, cg=tid&3) owns
// query row r, dim group cg (16 wide). fp32 compute; P aliased over K tile.
__global__ __launch_bounds__(256) void k_flash(const bf16_t* __restrict__ qkv,
                                               float* __restrict__ hres) {
  __shared__ float Qs[64 * 68];
  __shared__ float Ks[64 * 68];   // re-used as P after scores are consumed
  __shared__ float Vs[64 * 68];
  int hh = blockIdx.x;            // 0..15
  int qt = blockIdx.y;            // 0..15
  int tid = threadIdx.x;
  int sr = tid >> 5;              // staging: 8 rows/pass
  int sd = (tid & 31) * 2;        // 2 consecutive dims per thread
  const bf16_t* base = qkv + hh * HDM;
#pragma unroll
  for (int i = 0; i < 8; i++) {
    int rr = sr + 8 * i;
    unsigned u = *(const unsigned*)(base + (size_t)(qt * 64 + rr) * (3 * DM) + sd);
    Qs[rr * 68 + sd]     = __uint_as_float(u << 16);
    Qs[rr * 68 + sd + 1] = __uint_as_float(u & 0xffff0000u);
  }
  __syncthreads();
  int r = tid >> 2, cg = tid & 3;
  float4 qreg[16];
  {
    const float4* q4 = (const float4*)(Qs + r * 68);
#pragma unroll
    for (int i = 0; i < 16; i++) qreg[i] = q4[i];
  }
  float o[16];
#pragma unroll
  for (int i = 0; i < 16; i++) o[i] = 0.f;
  float m = -1e30f, l = 0.f;

  for (int st = 0; st <= qt; st++) {
    __syncthreads();
#pragma unroll
    for (int i = 0; i < 8; i++) {
      int rr = sr + 8 * i;
      size_t rowoff = (size_t)(st * 64 + rr) * (3 * DM);
      unsigned uk = *(const unsigned*)(base + rowoff + DM + sd);
      unsigned uv = *(const unsigned*)(base + rowoff + 2 * DM + sd);
      Ks[rr * 68 + sd]     = __uint_as_float(uk << 16);
      Ks[rr * 68 + sd + 1] = __uint_as_float(uk & 0xffff0000u);
      Vs[rr * 68 + sd]     = __uint_as_float(uv << 16);
      Vs[rr * 68 + sd + 1] = __uint_as_float(uv & 0xffff0000u);
    }
    __syncthreads();
    float s[16];
#pragma unroll
    for (int j = 0; j < 16; j++) {
      int col = cg * 16 + j;
      const float4* k4 = (const float4*)(Ks + col * 68);
      float acc = 0.f;
#pragma unroll
      for (int d4 = 0; d4 < 16; d4++) {
        float4 qa = qreg[d4], ka = k4[d4];
        acc += qa.x * ka.x; acc += qa.y * ka.y;
        acc += qa.z * ka.z; acc += qa.w * ka.w;
      }
      s[j] = acc * 0.125f;
    }
    if (st == qt) {
#pragma unroll
      for (int j = 0; j < 16; j++)
        if (cg * 16 + j > r) s[j] = -1e30f;
    }
    float mt = s[0];
#pragma unroll
    for (int j = 1; j < 16; j++) mt = fmaxf(mt, s[j]);
    mt = fmaxf(mt, __shfl_xor(mt, 1));
    mt = fmaxf(mt, __shfl_xor(mt, 2));
    float mn = fmaxf(m, mt);
    float corr = __expf(m - mn);
    __syncthreads();  // all lanes done reading Ks before P overwrite
    float psum = 0.f;
#pragma unroll
    for (int j = 0; j < 16; j++) {
      float p = __expf(s[j] - mn);
      Ks[r * 68 + cg * 16 + j] = p;
      psum += p;
    }
    psum += __shfl_xor(psum, 1);
    psum += __shfl_xor(psum, 2);
    l = l * corr + psum;
    m = mn;
#pragma unroll
    for (int i = 0; i < 16; i++) o[i] *= corr;
    __syncthreads();  // P visible
    const float* prow = Ks + r * 68;
#pragma unroll 4
    for (int kk = 0; kk < 64; kk++) {
      float p = prow[kk];
      const float4* v4 = (const float4*)(Vs + kk * 68 + cg * 16);
      float4 a0 = v4[0], a1 = v4[1], a2 = v4[2], a3 = v4[3];
      o[0]  += p * a0.x; o[1]  += p * a0.y; o[2]  += p * a0.z; o[3]  += p * a0.w;
      o[4]  += p * a1.x; o[5]  += p * a1.y; o[6]  += p * a1.z; o[7]  += p * a1.w;
      o[8]  += p * a2.x; o[9]  += p * a2.y; o[10] += p * a2.z; o[11] += p * a2.w;
      o[12] += p * a3.x; o[13] += p * a3.y; o[14] += p * a3.z; o[15] += p * a3.w;
    }
  }
  float inv = 1.0f / l;
  float* op = hres + (size_t)(qt * 64 + r) * DM + hh * HDM + cg * 16;
#pragma unroll
  for (int j = 0; j < 16; j++) op[j] += o[j] * inv;
}

// logits (M=2) + log_softmax, one wave per token row
__global__ __launch_bounds__(256) void k_logits(const float* __restrict__ h,
    const float* __restrict__ w, const float* __restrict__ bz,
    float* __restrict__ out) {
  int row  = blockIdx.x * 4 + (threadIdx.x >> 6);
  int lane = threadIdx.x & 63;
  const float* hp = h + (size_t)row * DM;
  float s0 = 0.f, s1 = 0.f;
#pragma unroll
  for (int i = 0; i < 16; i++) {
    float v = hp[lane + 64 * i];
    s0 += v * w[lane + 64 * i];
    s1 += v * w[DM + lane + 64 * i];
  }
#pragma unroll
  for (int off = 32; off; off >>= 1) {
    s0 += __shfl_xor(s0, off);
    s1 += __shfl_xor(s1, off);
  }
  if (lane == 0) {
    float z0 = s0 + bz[0], z1 = s1 + bz[1];
    float mx  = fmaxf(z0, z1);
    float lse = mx + logf(expf(z0 - mx) + expf(z1 - mx));
    out[row * 2]     = z0 - lse;
    out[row * 2 + 1] = z1 - lse;
  }
}

extern "C" void kernel_launch(void* const* d_in, const int* in_sizes, int n_in,
                              void* d_out, int out_size, void* d_ws, size_t ws_size,
                              hipStream_t stream) {
  const int*   x     = (const int*)d_in[0];
  const float* tokE  = (const float*)d_in[1];
  const float* posE  = (const float*)d_in[2];
  const float* w_qkv = (const float*)d_in[3];
  const float* b_qkv = (const float*)d_in[4];
  const float* ln1g  = (const float*)d_in[5];
  const float* ln1b  = (const float*)d_in[6];
  const float* ln2g  = (const float*)d_in[7];
  const float* ln2b  = (const float*)d_in[8];
  const float* fw1   = (const float*)d_in[9];
  const float* fb1   = (const float*)d_in[10];
  const float* fw2   = (const float*)d_in[11];
  const float* fb2   = (const float*)d_in[12];
  const float* outw  = (const float*)d_in[13];
  const float* outb  = (const float*)d_in[14];
  float* out = (float*)d_out;

  const size_t NT = (size_t)BB * TS;  // 4096 tokens
  const size_t MB = 1024 * 1024;
  // Workspace: 30 MB total (32 MB budget proven safe in round 2).
  //   h fp32 [0,16MB): persistent residual stream.
  //   S = scratch [16MB, 30MB), time-shared:
  //     attention phase: wqkv_bf [0,6M) | a_bf [6M,8M) | qkv_bf [8M,14M)
  //     FF phase:        a2_bf [0,8M) | fw1_bf [8M,9M) | fw2_bf [9M,10M)
  //                      | f1_bf [10M,14M)    (slab width 512 over DFF)
  float* h = (float*)d_ws;
  char*  S = (char*)d_ws + 16 * MB;
  bf16_t* wqkv_bf = (bf16_t*)S;
  bf16_t* a_bf    = (bf16_t*)(S + 6 * MB);
  bf16_t* qkv_bf  = (bf16_t*)(S + 8 * MB);
  bf16_t* a2_bf   = (bf16_t*)S;
  bf16_t* fw1_bf  = (bf16_t*)(S + 8 * MB);
  bf16_t* fw2_bf  = (bf16_t*)(S + 9 * MB);
  bf16_t* f1_bf   = (bf16_t*)(S + 10 * MB);

  k_embed<<<(NT * DM) / 256, 256, 0, stream>>>(x, tokE, posE, h);
  for (int l = 0; l < NLY; l++) {
    // --- attention phase, per batch element (LN1 out read-only vs hb acc) ---
    k_cvt<<<3 * DM, 256, 0, stream>>>(w_qkv + (size_t)l * 3 * DM * DM,
                                      wqkv_bf, DM, 10);
    for (int b = 0; b < BB; b++) {
      float* hb = h + (size_t)b * TS * DM;
      k_ln<<<TS / 4, 256, 0, stream>>>(hb, ln1g + l * DM, ln1b + l * DM,
                                       nullptr, a_bf);
      k_gemm<false, false, bf16_t><<<dim3(3 * DM / 128, TS / 128), 256, 0, stream>>>(
          a_bf, wqkv_bf, b_qkv + l * 3 * DM, qkv_bf, TS, 3 * DM, DM);
      k_flash<<<dim3(NHD, TS / 64), 256, 0, stream>>>(qkv_bf, hb);  // hb += attn
    }
    // --- ln2: h (fp32, residual basis) + a2_bf (bf16, read-only FF1 input) ---
    k_ln<<<NT / 4, 256, 0, stream>>>(h, ln2g + l * DM, ln2b + l * DM, h, a2_bf);
    // --- FF phase: 8 slabs of 512 over DFF; FF1 reads a2_bf (pristine),
    //     FF2 accumulates into h — no read-after-write hazard. ---
    for (int s = 0; s < 8; s++) {
      k_cvt<<<512, 256, 0, stream>>>(fw1 + (size_t)l * DFF * DM + (size_t)s * 512 * DM,
                                     fw1_bf, DM, 10);
      k_cvt<<<512, 256, 0, stream>>>(fw2 + (size_t)l * DM * DFF + s * 512,
                                     fw2_bf, DFF, 9);
      k_gemm<true, false, bf16_t><<<dim3(512 / 128, NT / 128), 256, 0, stream>>>(
          a2_bf, fw1_bf, fb1 + l * DFF + s * 512, f1_bf, NT, 512, DM);
      k_gemm<false, true, float><<<dim3(DM / 128, NT / 128), 256, 0, stream>>>(
          f1_bf, fw2_bf, s == 0 ? fb2 + l * DM : nullptr, h, NT, DM, 512);
    }
  }
  k_logits<<<NT / 4, 256, 0, stream>>>(h, outw, outb, out);
}

// Round 5
// 3857.590 us; speedup vs baseline: 3.6166x; 2.0090x over previous
//
#include <hip/hip_runtime.h>
#include <cstddef>
#include <cstdint>

// Model dims
#define BB   4
#define TS   1024
#define DM   1024
#define DFF  4096
#define NHD  16
#define HDM  64
#define NLY  4
#define TOKD 256
#define POSD 768

typedef __bf16 bf16_t;
typedef __bf16 bf16x4 __attribute__((ext_vector_type(4)));
typedef __bf16 bf16x8 __attribute__((ext_vector_type(8)));
typedef float  f32x4  __attribute__((ext_vector_type(4)));

#define GLOAD_LDS16(gp, lp)                                                  \
  __builtin_amdgcn_global_load_lds(                                          \
      (const __attribute__((address_space(1))) void*)(gp),                   \
      (__attribute__((address_space(3))) void*)(lp), 16, 0, 0)

__device__ __forceinline__ float gelu_f(float x) {
  float x3 = x * x * x;
  return 0.5f * x * (1.0f + tanhf(0.7978845608028654f * (x + 0.044715f * x3)));
}

// h[b,t,:] = [tok_emb[x_in[b,t]], pos_emb[t]]; x_in = shift-right with BOS=1
__global__ __launch_bounds__(256) void k_embed(const int* __restrict__ x,
    const float* __restrict__ tok, const float* __restrict__ pos,
    float* __restrict__ h) {
  int idx = blockIdx.x * 256 + threadIdx.x;
  int d  = idx & (DM - 1);
  int bt = idx >> 10;
  int t  = bt & (TS - 1);
  int b  = bt >> 10;
  float v;
  if (d < TOKD) {
    int tk = (t == 0) ? 1 : x[b * TS + t - 1];
    v = tok[tk * TOKD + d];
  } else {
    v = pos[t * POSD + (d - TOKD)];
  }
  h[idx] = v;
}

// fp32 -> bf16 convert. dst is dense [rows, 1<<shift]; src has row stride
// `stride` (elements). One float4 per thread; grid = rows*cols/1024.
__global__ __launch_bounds__(256) void k_cvt(const float* __restrict__ src,
    bf16_t* __restrict__ dst, int stride, int shift) {
  int idx = (blockIdx.x * 256 + threadIdx.x) * 4;
  int r = idx >> shift, c = idx & ((1 << shift) - 1);
  float4 v = *(const float4*)(src + (size_t)r * stride + c);
  bf16x4 o = { (bf16_t)v.x, (bf16_t)v.y, (bf16_t)v.z, (bf16_t)v.w };
  *(bf16x4*)(dst + idx) = o;
}

// One wave per row (1024 dims, 16 elems/lane). Optional fp32 / bf16 outputs.
__global__ __launch_bounds__(256) void k_ln(const float* __restrict__ in,
    const float* __restrict__ g, const float* __restrict__ bta,
    float* __restrict__ out_f, bf16_t* __restrict__ out_bf) {
  int row  = blockIdx.x * 4 + (threadIdx.x >> 6);
  int lane = threadIdx.x & 63;
  const float* p = in + (size_t)row * DM;
  float vals[16];
  float s = 0.f, s2 = 0.f;
#pragma unroll
  for (int i = 0; i < 16; i++) {
    float v = p[lane + 64 * i];
    vals[i] = v; s += v; s2 += v * v;
  }
#pragma unroll
  for (int off = 32; off; off >>= 1) {
    s  += __shfl_xor(s, off);
    s2 += __shfl_xor(s2, off);
  }
  float mu  = s * (1.f / DM);
  float var = s2 * (1.f / DM) - mu * mu;
  float rs  = rsqrtf(var + 1e-5f);
#pragma unroll
  for (int i = 0; i < 16; i++) {
    int d = lane + 64 * i;
    float v = (vals[i] - mu) * rs * g[d] + bta[d];
    if (out_f)  out_f[(size_t)row * DM + d] = v;
    if (out_bf) out_bf[(size_t)row * DM + d] = (bf16_t)v;
  }
}

// MFMA bf16 GEMM: C[M,N] = epi(A[M,K] * B[N,K]^T + bias[N])
// 128x128 C-tile per 256-thread block (4 waves, 2x2 of 64x64), BK=32,
// 16x16x32 MFMA, 4x4 fragments per wave. A,B bf16 via global_load_lds w=16.
// ACC: C[m][n] += v. Requires M%128==N%128==0, K%32==0, strides K / N.
template <bool GELU, bool ACC, typename CT>
__global__ __launch_bounds__(256) void k_gemm(
    const bf16_t* __restrict__ A, const bf16_t* __restrict__ B,
    const float* __restrict__ bias, CT* __restrict__ C,
    int M, int N, int K) {
  __shared__ __align__(16) bf16_t As[128 * 32];
  __shared__ __align__(16) bf16_t Bs[128 * 32];
  const int tid  = threadIdx.x;
  const int wave = tid >> 6, lane = tid & 63;
  const int m0 = blockIdx.y * 128, n0 = blockIdx.x * 128;
  const int wm = (wave >> 1) * 64, wn = (wave & 1) * 64;
  f32x4 acc[4][4];
#pragma unroll
  for (int i = 0; i < 4; i++)
#pragma unroll
    for (int j = 0; j < 4; j++) acc[i][j] = {0.f, 0.f, 0.f, 0.f};

  const int srow = wave * 16 + (lane >> 2);
  const int scol = (lane & 3) * 8;
  const bf16_t* Ag = A + (size_t)(m0 + srow) * K + scol;
  const bf16_t* Bg = B + (size_t)(n0 + srow) * K + scol;
  bf16_t* AsW = As + wave * 16 * 32;
  bf16_t* BsW = Bs + wave * 16 * 32;
  const int fr = lane & 15, fq = lane >> 4;

  for (int k0 = 0; k0 < K; k0 += 32) {
    __syncthreads();
    GLOAD_LDS16(Ag + k0, AsW);
    GLOAD_LDS16(Ag + (size_t)64 * K + k0, AsW + 64 * 32);
    GLOAD_LDS16(Bg + k0, BsW);
    GLOAD_LDS16(Bg + (size_t)64 * K + k0, BsW + 64 * 32);
    __syncthreads();
    bf16x8 af[4], bfv[4];
#pragma unroll
    for (int i = 0; i < 4; i++)
      af[i] = *(const bf16x8*)&As[(wm + i * 16 + fr) * 32 + fq * 8];
#pragma unroll
    for (int j = 0; j < 4; j++)
      bfv[j] = *(const bf16x8*)&Bs[(wn + j * 16 + fr) * 32 + fq * 8];
#pragma unroll
    for (int i = 0; i < 4; i++)
#pragma unroll
      for (int j = 0; j < 4; j++)
        acc[i][j] = __builtin_amdgcn_mfma_f32_16x16x32_bf16(
            af[i], bfv[j], acc[i][j], 0, 0, 0);
  }
#pragma unroll
  for (int i = 0; i < 4; i++) {
#pragma unroll
    for (int j = 0; j < 4; j++) {
#pragma unroll
      for (int r = 0; r < 4; r++) {
        int m = m0 + wm + i * 16 + fq * 4 + r;
        int n = n0 + wn + j * 16 + fr;
        float v = acc[i][j][r];
        if (bias) v += bias[n];
        if (GELU) v = gelu_f(v);
        size_t off = (size_t)m * N + n;
        if (ACC) C[off] = (CT)((float)C[off] + v);
        else     C[off] = (CT)v;
      }
    }
  }
}

// MFMA flash attention, one batch element. qkv bf16 [T, 3*DM]; hres += attn
// (fp32 accumulate into residual stream). Block 256 = one (head, 64-q-tile);
// wave w owns q-rows w*16..w*16+15. Per 64-wide K-tile: QK^T (8 mfma/wave),
// online softmax in C-layout regs, P->bf16 via LDS (C-layout -> A-layout
// round trip, m120), PV (8 mfma/wave). V staged transposed (Vt[dim][s]) since
// the PV B-operand needs V^T rows. LDS stride 72 breaks bank degeneracy.
__global__ __launch_bounds__(256) void k_flash(const bf16_t* __restrict__ qkv,
                                               float* __restrict__ hres) {
  __shared__ __align__(16) bf16_t Qs[64 * 72];   // re-used as P after Q->regs
  __shared__ __align__(16) bf16_t Ks[64 * 72];
  __shared__ __align__(16) bf16_t Vt[64 * 72];   // [dim][s]
  const int hh = blockIdx.x, qt = blockIdx.y;
  const int tid = threadIdx.x;
  const int w = tid >> 6, lane = tid & 63;
  const int fr = lane & 15, fq = lane >> 4;
  const int sr = tid >> 2, seg = tid & 3;        // staging: row, 16-col segment
  const bf16_t* base = qkv + hh * HDM;
  bf16_t* Ps = Qs;                               // alias: Qs dead after aq load

  // stage Q tile (each wave writes its own 16 rows)
  {
    const bf16_t* qrow = base + (size_t)(qt * 64 + sr) * (3 * DM) + seg * 16;
    *(bf16x8*)&Qs[sr * 72 + seg * 16]     = *(const bf16x8*)qrow;
    *(bf16x8*)&Qs[sr * 72 + seg * 16 + 8] = *(const bf16x8*)(qrow + 8);
  }
  __syncthreads();
  bf16x8 aq[2];   // A-frag: A[m=fr][k=fq*8+j (+32*half)]
  aq[0] = *(const bf16x8*)&Qs[(w * 16 + fr) * 72 + fq * 8];
  aq[1] = *(const bf16x8*)&Qs[(w * 16 + fr) * 72 + 32 + fq * 8];

  f32x4 o[4];
#pragma unroll
  for (int d = 0; d < 4; d++) o[d] = {0.f, 0.f, 0.f, 0.f};
  float mval[4] = {-1e30f, -1e30f, -1e30f, -1e30f};
  float lsum[4] = {0.f, 0.f, 0.f, 0.f};

  for (int st = 0; st <= qt; st++) {
    __syncthreads();   // previous iteration's Ks/Vt/Ps readers done
    {
      size_t rowoff = (size_t)(st * 64 + sr) * (3 * DM);
      const bf16_t* krow = base + rowoff + DM + seg * 16;
      *(bf16x8*)&Ks[sr * 72 + seg * 16]     = *(const bf16x8*)krow;
      *(bf16x8*)&Ks[sr * 72 + seg * 16 + 8] = *(const bf16x8*)(krow + 8);
      const bf16_t* vrow = base + rowoff + 2 * DM + seg * 16;
      bf16x8 v0 = *(const bf16x8*)vrow;
      bf16x8 v1 = *(const bf16x8*)(vrow + 8);
#pragma unroll
      for (int j = 0; j < 8; j++) Vt[(seg * 16 + j) * 72 + sr]     = v0[j];
#pragma unroll
      for (int j = 0; j < 8; j++) Vt[(seg * 16 + 8 + j) * 72 + sr] = v1[j];
    }
    __syncthreads();
    // S = Q K^T : 4 col-tiles x 2 k-halves
    f32x4 sacc[4];
#pragma unroll
    for (int j = 0; j < 4; j++) sacc[j] = {0.f, 0.f, 0.f, 0.f};
#pragma unroll
    for (int j = 0; j < 4; j++)
#pragma unroll
      for (int hf = 0; hf < 2; hf++) {
        bf16x8 bk = *(const bf16x8*)&Ks[(j * 16 + fr) * 72 + hf * 32 + fq * 8];
        sacc[j] = __builtin_amdgcn_mfma_f32_16x16x32_bf16(aq[hf], bk, sacc[j],
                                                          0, 0, 0);
      }
    // scale + causal mask (C-layout: col = j*16+fr, row = w*16+fq*4+r)
#pragma unroll
    for (int j = 0; j < 4; j++)
#pragma unroll
      for (int r = 0; r < 4; r++) {
        float s = sacc[j][r] * 0.125f;
        if (st == qt && (j * 16 + fr) > (w * 16 + fq * 4 + r)) s = -1e30f;
        sacc[j][r] = s;
      }
    // online softmax: per-reg row max/sum, reduced across the 16-lane quad
    float corr[4];
#pragma unroll
    for (int r = 0; r < 4; r++) {
      float v = fmaxf(fmaxf(sacc[0][r], sacc[1][r]),
                      fmaxf(sacc[2][r], sacc[3][r]));
      v = fmaxf(v, __shfl_xor(v, 1));
      v = fmaxf(v, __shfl_xor(v, 2));
      v = fmaxf(v, __shfl_xor(v, 4));
      v = fmaxf(v, __shfl_xor(v, 8));
      float mn = fmaxf(mval[r], v);
      corr[r] = __expf(mval[r] - mn);
      mval[r] = mn;
      lsum[r] *= corr[r];
    }
#pragma unroll
    for (int d = 0; d < 4; d++)
#pragma unroll
      for (int r = 0; r < 4; r++) o[d][r] *= corr[r];
    float rsum[4] = {0.f, 0.f, 0.f, 0.f};
#pragma unroll
    for (int j = 0; j < 4; j++)
#pragma unroll
      for (int r = 0; r < 4; r++) {
        float p = __expf(sacc[j][r] - mval[r]);
        rsum[r] += p;
        Ps[(w * 16 + fq * 4 + r) * 72 + j * 16 + fr] = (bf16_t)p;
      }
#pragma unroll
    for (int r = 0; r < 4; r++) {
      float v = rsum[r];
      v += __shfl_xor(v, 1);
      v += __shfl_xor(v, 2);
      v += __shfl_xor(v, 4);
      v += __shfl_xor(v, 8);
      lsum[r] += v;
    }
    __syncthreads();   // Ps writes visible before A-frag reads
    bf16x8 ap[2];
    ap[0] = *(const bf16x8*)&Ps[(w * 16 + fr) * 72 + fq * 8];
    ap[1] = *(const bf16x8*)&Ps[(w * 16 + fr) * 72 + 32 + fq * 8];
#pragma unroll
    for (int d = 0; d < 4; d++)
#pragma unroll
      for (int hf = 0; hf < 2; hf++) {
        bf16x8 bv = *(const bf16x8*)&Vt[(d * 16 + fr) * 72 + hf * 32 + fq * 8];
        o[d] = __builtin_amdgcn_mfma_f32_16x16x32_bf16(ap[hf], bv, o[d],
                                                       0, 0, 0);
      }
  }
  // epilogue: hres += o / l   (rows w*16+fq*4+r, dims d*16+fr)
#pragma unroll
  for (int r = 0; r < 4; r++) {
    float inv = 1.0f / lsum[r];
    float* row = hres + (size_t)(qt * 64 + w * 16 + fq * 4 + r) * DM + hh * HDM;
#pragma unroll
    for (int d = 0; d < 4; d++) row[d * 16 + fr] += o[d][r] * inv;
  }
}

// logits (M=2) + log_softmax, one wave per token row
__global__ __launch_bounds__(256) void k_logits(const float* __restrict__ h,
    const float* __restrict__ w, const float* __restrict__ bz,
    float* __restrict__ out) {
  int row  = blockIdx.x * 4 + (threadIdx.x >> 6);
  int lane = threadIdx.x & 63;
  const float* hp = h + (size_t)row * DM;
  float s0 = 0.f, s1 = 0.f;
#pragma unroll
  for (int i = 0; i < 16; i++) {
    float v = hp[lane + 64 * i];
    s0 += v * w[lane + 64 * i];
    s1 += v * w[DM + lane + 64 * i];
  }
#pragma unroll
  for (int off = 32; off; off >>= 1) {
    s0 += __shfl_xor(s0, off);
    s1 += __shfl_xor(s1, off);
  }
  if (lane == 0) {
    float z0 = s0 + bz[0], z1 = s1 + bz[1];
    float mx  = fmaxf(z0, z1);
    float lse = mx + logf(expf(z0 - mx) + expf(z1 - mx));
    out[row * 2]     = z0 - lse;
    out[row * 2 + 1] = z1 - lse;
  }
}

extern "C" void kernel_launch(void* const* d_in, const int* in_sizes, int n_in,
                              void* d_out, int out_size, void* d_ws, size_t ws_size,
                              hipStream_t stream) {
  const int*   x     = (const int*)d_in[0];
  const float* tokE  = (const float*)d_in[1];
  const float* posE  = (const float*)d_in[2];
  const float* w_qkv = (const float*)d_in[3];
  const float* b_qkv = (const float*)d_in[4];
  const float* ln1g  = (const float*)d_in[5];
  const float* ln1b  = (const float*)d_in[6];
  const float* ln2g  = (const float*)d_in[7];
  const float* ln2b  = (const float*)d_in[8];
  const float* fw1   = (const float*)d_in[9];
  const float* fb1   = (const float*)d_in[10];
  const float* fw2   = (const float*)d_in[11];
  const float* fb2   = (const float*)d_in[12];
  const float* outw  = (const float*)d_in[13];
  const float* outb  = (const float*)d_in[14];
  float* out = (float*)d_out;

  const size_t NT = (size_t)BB * TS;  // 4096 tokens
  const size_t MB = 1024 * 1024;
  // Workspace: 30 MB total (32 MB proven safe).
  //   h fp32 [0,16MB): persistent residual stream.
  //   S = scratch [16MB, 30MB), time-shared:
  //     attention phase: wqkv_bf [0,6M) | a_bf [6M,8M) | qkv_bf [8M,14M)
  //     FF phase:        a2_bf [0,8M) | fw1_bf [8M,9M) | fw2_bf [9M,10M)
  //                      | f1_bf [10M,14M)    (slab width 512 over DFF)
  float* h = (float*)d_ws;
  char*  S = (char*)d_ws + 16 * MB;
  bf16_t* wqkv_bf = (bf16_t*)S;
  bf16_t* a_bf    = (bf16_t*)(S + 6 * MB);
  bf16_t* qkv_bf  = (bf16_t*)(S + 8 * MB);
  bf16_t* a2_bf   = (bf16_t*)S;
  bf16_t* fw1_bf  = (bf16_t*)(S + 8 * MB);
  bf16_t* fw2_bf  = (bf16_t*)(S + 9 * MB);
  bf16_t* f1_bf   = (bf16_t*)(S + 10 * MB);

  k_embed<<<(NT * DM) / 256, 256, 0, stream>>>(x, tokE, posE, h);
  for (int l = 0; l < NLY; l++) {
    // --- attention phase, per batch element ---
    k_cvt<<<3 * DM, 256, 0, stream>>>(w_qkv + (size_t)l * 3 * DM * DM,
                                      wqkv_bf, DM, 10);
    for (int b = 0; b < BB; b++) {
      float* hb = h + (size_t)b * TS * DM;
      k_ln<<<TS / 4, 256, 0, stream>>>(hb, ln1g + l * DM, ln1b + l * DM,
                                       nullptr, a_bf);
      k_gemm<false, false, bf16_t><<<dim3(3 * DM / 128, TS / 128), 256, 0, stream>>>(
          a_bf, wqkv_bf, b_qkv + l * 3 * DM, qkv_bf, TS, 3 * DM, DM);
      k_flash<<<dim3(NHD, TS / 64), 256, 0, stream>>>(qkv_bf, hb);  // hb += attn
    }
    // --- ln2: h (fp32 residual basis) + a2_bf (bf16 read-only FF1 input) ---
    k_ln<<<NT / 4, 256, 0, stream>>>(h, ln2g + l * DM, ln2b + l * DM, h, a2_bf);
    // --- FF phase: 8 slabs of 512 over DFF; FF2 accumulates into h ---
    for (int s = 0; s < 8; s++) {
      k_cvt<<<512, 256, 0, stream>>>(fw1 + (size_t)l * DFF * DM + (size_t)s * 512 * DM,
                                     fw1_bf, DM, 10);
      k_cvt<<<512, 256, 0, stream>>>(fw2 + (size_t)l * DM * DFF + s * 512,
                                     fw2_bf, DFF, 9);
      k_gemm<true, false, bf16_t><<<dim3(512 / 128, NT / 128), 256, 0, stream>>>(
          a2_bf, fw1_bf, fb1 + l * DFF + s * 512, f1_bf, NT, 512, DM);
      k_gemm<false, true, float><<<dim3(DM / 128, NT / 128), 256, 0, stream>>>(
          f1_bf, fw2_bf, s == 0 ? fb2 + l * DM : nullptr, h, NT, DM, 512);
    }
  }
  k_logits<<<NT / 4, 256, 0, stream>>>(h, outw, outb, out);
}

// Round 6
// 2221.378 us; speedup vs baseline: 6.2805x; 1.7366x over previous
//
#include <hip/hip_runtime.h>
#include <cstddef>
#include <cstdint>

// Model dims
#define BB   4
#define TS   1024
#define DM   1024
#define DFF  4096
#define NHD  16
#define HDM  64
#define NLY  4
#define TOKD 256
#define POSD 768

typedef __bf16 bf16_t;
typedef __bf16 bf16x4 __attribute__((ext_vector_type(4)));
typedef __bf16 bf16x8 __attribute__((ext_vector_type(8)));
typedef float  f32x4  __attribute__((ext_vector_type(4)));

#define GLOAD_LDS16(gp, lp)                                                  \
  __builtin_amdgcn_global_load_lds(                                          \
      (const __attribute__((address_space(1))) void*)(gp),                   \
      (__attribute__((address_space(3))) void*)(lp), 16, 0, 0)

__device__ __forceinline__ float gelu_f(float x) {
  float x3 = x * x * x;
  return 0.5f * x * (1.0f + tanhf(0.7978845608028654f * (x + 0.044715f * x3)));
}

// h[b,t,:] = [tok_emb[x_in[b,t]], pos_emb[t]] -> bf16. 4 elems/thread.
__global__ __launch_bounds__(256) void k_embed(const int* __restrict__ x,
    const float* __restrict__ tok, const float* __restrict__ pos,
    bf16_t* __restrict__ h) {
  int idx = (blockIdx.x * 256 + threadIdx.x) * 4;
  int d  = idx & (DM - 1);
  int bt = idx >> 10;
  int t  = bt & (TS - 1);
  int b  = bt >> 10;
  float4 v;
  if (d < TOKD) {
    int tk = (t == 0) ? 1 : x[b * TS + t - 1];
    v = *(const float4*)(tok + tk * TOKD + d);
  } else {
    v = *(const float4*)(pos + (size_t)t * POSD + (d - TOKD));
  }
  bf16x4 o = { (bf16_t)v.x, (bf16_t)v.y, (bf16_t)v.z, (bf16_t)v.w };
  *(bf16x4*)(h + idx) = o;
}

// LayerNorm, one wave per 1024-dim row, bf16 in, bf16 out(s) (either may be
// null). fp32 statistics. Lane owns 16 contiguous elems.
__global__ __launch_bounds__(256) void k_ln(const bf16_t* __restrict__ in,
    const float* __restrict__ g, const float* __restrict__ bta,
    bf16_t* __restrict__ out1, bf16_t* __restrict__ out2) {
  int row  = blockIdx.x * 4 + (threadIdx.x >> 6);
  int lane = threadIdx.x & 63;
  const bf16_t* p = in + (size_t)row * DM + lane * 16;
  bf16x8 v0 = *(const bf16x8*)p;
  bf16x8 v1 = *(const bf16x8*)(p + 8);
  float vals[16];
  float s = 0.f, s2 = 0.f;
#pragma unroll
  for (int i = 0; i < 8; i++) { vals[i] = (float)v0[i]; vals[8 + i] = (float)v1[i]; }
#pragma unroll
  for (int i = 0; i < 16; i++) { s += vals[i]; s2 += vals[i] * vals[i]; }
#pragma unroll
  for (int off = 32; off; off >>= 1) {
    s  += __shfl_xor(s, off);
    s2 += __shfl_xor(s2, off);
  }
  float mu  = s * (1.f / DM);
  float var = s2 * (1.f / DM) - mu * mu;
  float rs  = rsqrtf(var + 1e-5f);
  bf16x8 o0, o1;
#pragma unroll
  for (int i = 0; i < 16; i++) {
    int d = lane * 16 + i;
    float v = (vals[i] - mu) * rs * g[d] + bta[d];
    if (i < 8) o0[i] = (bf16_t)v; else o1[i - 8] = (bf16_t)v;
  }
  size_t off = (size_t)row * DM + lane * 16;
  if (out1) { *(bf16x8*)(out1 + off) = o0; *(bf16x8*)(out1 + off + 8) = o1; }
  if (out2) { *(bf16x8*)(out2 + off) = o0; *(bf16x8*)(out2 + off + 8) = o1; }
}

// MFMA bf16 GEMM: C[M,N] = epi(A[M,K] * B[N,K]^T + bias[N])
// A: bf16, row stride K, staged via global_load_lds w=16.
// B: fp32 weights, row stride ldb, staged+converted to bf16 in LDS (weights
//    are L2-resident; folding the cvt here kills all k_cvt dispatches).
// C: bf16, row stride N. ACC: C += (read-modify-write, bf16 round).
// 128x128 tile / 256 threads / 4 waves (2x2 of 64x64), BK=32, 16x16x32 MFMA.
template <bool GELU, bool ACC>
__global__ __launch_bounds__(256) void k_gemm(
    const bf16_t* __restrict__ A, const float* __restrict__ B,
    const float* __restrict__ bias, bf16_t* __restrict__ C,
    int M, int N, int K, int ldb) {
  __shared__ __align__(16) bf16_t As[128 * 32];
  __shared__ __align__(16) bf16_t Bs[128 * 32];
  const int tid  = threadIdx.x;
  const int wave = tid >> 6, lane = tid & 63;
  const int m0 = blockIdx.y * 128, n0 = blockIdx.x * 128;
  const int wm = (wave >> 1) * 64, wn = (wave & 1) * 64;
  f32x4 acc[4][4];
#pragma unroll
  for (int i = 0; i < 4; i++)
#pragma unroll
    for (int j = 0; j < 4; j++) acc[i][j] = {0.f, 0.f, 0.f, 0.f};

  // A staging: wave owns 16 rows/issue; DMA lane->16B rule gives [16,32] tile
  const int srow = wave * 16 + (lane >> 2);
  const int scol = (lane & 3) * 8;
  const bf16_t* Ag = A + (size_t)(m0 + srow) * K + scol;
  bf16_t* AsW = As + wave * 16 * 32;
  // B staging (fp32 -> bf16): thread covers rows {tid>>3 + 32i}, 4 cols
  const int brow = tid >> 3;
  const int bcol = (tid & 7) * 4;
  const float* Bg = B + (size_t)(n0 + brow) * ldb + bcol;
  const int fr = lane & 15, fq = lane >> 4;

  for (int k0 = 0; k0 < K; k0 += 32) {
    __syncthreads();
    GLOAD_LDS16(Ag + k0, AsW);
    GLOAD_LDS16(Ag + (size_t)64 * K + k0, AsW + 64 * 32);
#pragma unroll
    for (int i = 0; i < 4; i++) {
      float4 v = *(const float4*)(Bg + (size_t)(i * 32) * ldb + k0);
      bf16x4 o = { (bf16_t)v.x, (bf16_t)v.y, (bf16_t)v.z, (bf16_t)v.w };
      *(bf16x4*)&Bs[(brow + i * 32) * 32 + bcol] = o;
    }
    __syncthreads();   // drains vmcnt (DMA) + lgkmcnt (ds_write)
    bf16x8 af[4], bfv[4];
#pragma unroll
    for (int i = 0; i < 4; i++)
      af[i] = *(const bf16x8*)&As[(wm + i * 16 + fr) * 32 + fq * 8];
#pragma unroll
    for (int j = 0; j < 4; j++)
      bfv[j] = *(const bf16x8*)&Bs[(wn + j * 16 + fr) * 32 + fq * 8];
#pragma unroll
    for (int i = 0; i < 4; i++)
#pragma unroll
      for (int j = 0; j < 4; j++)
        acc[i][j] = __builtin_amdgcn_mfma_f32_16x16x32_bf16(
            af[i], bfv[j], acc[i][j], 0, 0, 0);
  }
  // epilogue: C/D layout col = lane&15, row = (lane>>4)*4 + reg  [m89]
#pragma unroll
  for (int i = 0; i < 4; i++) {
#pragma unroll
    for (int j = 0; j < 4; j++) {
#pragma unroll
      for (int r = 0; r < 4; r++) {
        int m = m0 + wm + i * 16 + fq * 4 + r;
        int n = n0 + wn + j * 16 + fr;
        float v = acc[i][j][r];
        if (bias) v += bias[n];
        if (GELU) v = gelu_f(v);
        size_t off = (size_t)m * N + n;
        if (ACC) C[off] = (bf16_t)((float)C[off] + v);
        else     C[off] = (bf16_t)v;
      }
    }
  }
}

// MFMA flash attention. qkv bf16 [2*TS, 3*DM] (2 batches); hres (bf16) += attn.
// Grid (head, q-tile, batch-in-group). Wave w owns q-rows w*16..+15.
// Per 64-wide K-tile: QK^T (8 mfma/wave), online softmax in C-layout regs,
// P->bf16 via LDS (C->A layout round trip), PV (8 mfma/wave). V staged
// transposed. LDS stride 72 breaks bank degeneracy.
__global__ __launch_bounds__(256) void k_flash(const bf16_t* __restrict__ qkv,
                                               bf16_t* __restrict__ hres) {
  __shared__ __align__(16) bf16_t Qs[64 * 72];   // re-used as P after Q->regs
  __shared__ __align__(16) bf16_t Ks[64 * 72];
  __shared__ __align__(16) bf16_t Vt[64 * 72];   // [dim][s]
  const int hh = blockIdx.x, qt = blockIdx.y, bz = blockIdx.z;
  const int tid = threadIdx.x;
  const int w = tid >> 6, lane = tid & 63;
  const int fr = lane & 15, fq = lane >> 4;
  const int sr = tid >> 2, seg = tid & 3;
  const bf16_t* base = qkv + (size_t)bz * TS * (3 * DM) + hh * HDM;
  bf16_t* Ps = Qs;

  {
    const bf16_t* qrow = base + (size_t)(qt * 64 + sr) * (3 * DM) + seg * 16;
    *(bf16x8*)&Qs[sr * 72 + seg * 16]     = *(const bf16x8*)qrow;
    *(bf16x8*)&Qs[sr * 72 + seg * 16 + 8] = *(const bf16x8*)(qrow + 8);
  }
  __syncthreads();
  bf16x8 aq[2];
  aq[0] = *(const bf16x8*)&Qs[(w * 16 + fr) * 72 + fq * 8];
  aq[1] = *(const bf16x8*)&Qs[(w * 16 + fr) * 72 + 32 + fq * 8];

  f32x4 o[4];
#pragma unroll
  for (int d = 0; d < 4; d++) o[d] = {0.f, 0.f, 0.f, 0.f};
  float mval[4] = {-1e30f, -1e30f, -1e30f, -1e30f};
  float lsum[4] = {0.f, 0.f, 0.f, 0.f};

  for (int st = 0; st <= qt; st++) {
    __syncthreads();
    {
      size_t rowoff = (size_t)(st * 64 + sr) * (3 * DM);
      const bf16_t* krow = base + rowoff + DM + seg * 16;
      *(bf16x8*)&Ks[sr * 72 + seg * 16]     = *(const bf16x8*)krow;
      *(bf16x8*)&Ks[sr * 72 + seg * 16 + 8] = *(const bf16x8*)(krow + 8);
      const bf16_t* vrow = base + rowoff + 2 * DM + seg * 16;
      bf16x8 v0 = *(const bf16x8*)vrow;
      bf16x8 v1 = *(const bf16x8*)(vrow + 8);
#pragma unroll
      for (int j = 0; j < 8; j++) Vt[(seg * 16 + j) * 72 + sr]     = v0[j];
#pragma unroll
      for (int j = 0; j < 8; j++) Vt[(seg * 16 + 8 + j) * 72 + sr] = v1[j];
    }
    __syncthreads();
    f32x4 sacc[4];
#pragma unroll
    for (int j = 0; j < 4; j++) sacc[j] = {0.f, 0.f, 0.f, 0.f};
#pragma unroll
    for (int j = 0; j < 4; j++)
#pragma unroll
      for (int hf = 0; hf < 2; hf++) {
        bf16x8 bk = *(const bf16x8*)&Ks[(j * 16 + fr) * 72 + hf * 32 + fq * 8];
        sacc[j] = __builtin_amdgcn_mfma_f32_16x16x32_bf16(aq[hf], bk, sacc[j],
                                                          0, 0, 0);
      }
#pragma unroll
    for (int j = 0; j < 4; j++)
#pragma unroll
      for (int r = 0; r < 4; r++) {
        float s = sacc[j][r] * 0.125f;
        if (st == qt && (j * 16 + fr) > (w * 16 + fq * 4 + r)) s = -1e30f;
        sacc[j][r] = s;
      }
    float corr[4];
#pragma unroll
    for (int r = 0; r < 4; r++) {
      float v = fmaxf(fmaxf(sacc[0][r], sacc[1][r]),
                      fmaxf(sacc[2][r], sacc[3][r]));
      v = fmaxf(v, __shfl_xor(v, 1));
      v = fmaxf(v, __shfl_xor(v, 2));
      v = fmaxf(v, __shfl_xor(v, 4));
      v = fmaxf(v, __shfl_xor(v, 8));
      float mn = fmaxf(mval[r], v);
      corr[r] = __expf(mval[r] - mn);
      mval[r] = mn;
      lsum[r] *= corr[r];
    }
#pragma unroll
    for (int d = 0; d < 4; d++)
#pragma unroll
      for (int r = 0; r < 4; r++) o[d][r] *= corr[r];
    float rsum[4] = {0.f, 0.f, 0.f, 0.f};
#pragma unroll
    for (int j = 0; j < 4; j++)
#pragma unroll
      for (int r = 0; r < 4; r++) {
        float p = __expf(sacc[j][r] - mval[r]);
        rsum[r] += p;
        Ps[(w * 16 + fq * 4 + r) * 72 + j * 16 + fr] = (bf16_t)p;
      }
#pragma unroll
    for (int r = 0; r < 4; r++) {
      float v = rsum[r];
      v += __shfl_xor(v, 1);
      v += __shfl_xor(v, 2);
      v += __shfl_xor(v, 4);
      v += __shfl_xor(v, 8);
      lsum[r] += v;
    }
    __syncthreads();
    bf16x8 ap[2];
    ap[0] = *(const bf16x8*)&Ps[(w * 16 + fr) * 72 + fq * 8];
    ap[1] = *(const bf16x8*)&Ps[(w * 16 + fr) * 72 + 32 + fq * 8];
#pragma unroll
    for (int d = 0; d < 4; d++)
#pragma unroll
      for (int hf = 0; hf < 2; hf++) {
        bf16x8 bv = *(const bf16x8*)&Vt[(d * 16 + fr) * 72 + hf * 32 + fq * 8];
        o[d] = __builtin_amdgcn_mfma_f32_16x16x32_bf16(ap[hf], bv, o[d],
                                                       0, 0, 0);
      }
  }
#pragma unroll
  for (int r = 0; r < 4; r++) {
    float inv = 1.0f / lsum[r];
    bf16_t* row = hres + (size_t)bz * TS * DM +
                  (size_t)(qt * 64 + w * 16 + fq * 4 + r) * DM + hh * HDM;
#pragma unroll
    for (int d = 0; d < 4; d++) {
      int c = d * 16 + fr;
      row[c] = (bf16_t)((float)row[c] + o[d][r] * inv);
    }
  }
}

// logits (M=2) + log_softmax, one wave per token row, bf16 h
__global__ __launch_bounds__(256) void k_logits(const bf16_t* __restrict__ h,
    const float* __restrict__ w, const float* __restrict__ bz,
    float* __restrict__ out) {
  int row  = blockIdx.x * 4 + (threadIdx.x >> 6);
  int lane = threadIdx.x & 63;
  const bf16_t* hp = h + (size_t)row * DM + lane * 16;
  bf16x8 a0 = *(const bf16x8*)hp;
  bf16x8 a1 = *(const bf16x8*)(hp + 8);
  float s0 = 0.f, s1 = 0.f;
#pragma unroll
  for (int i = 0; i < 16; i++) {
    float v = (float)(i < 8 ? a0[i] : a1[i - 8]);
    int d = lane * 16 + i;
    s0 += v * w[d];
    s1 += v * w[DM + d];
  }
#pragma unroll
  for (int off = 32; off; off >>= 1) {
    s0 += __shfl_xor(s0, off);
    s1 += __shfl_xor(s1, off);
  }
  if (lane == 0) {
    float z0 = s0 + bz[0], z1 = s1 + bz[1];
    float mx  = fmaxf(z0, z1);
    float lse = mx + logf(expf(z0 - mx) + expf(z1 - mx));
    out[row * 2]     = z0 - lse;
    out[row * 2 + 1] = z1 - lse;
  }
}

extern "C" void kernel_launch(void* const* d_in, const int* in_sizes, int n_in,
                              void* d_out, int out_size, void* d_ws, size_t ws_size,
                              hipStream_t stream) {
  const int*   x     = (const int*)d_in[0];
  const float* tokE  = (const float*)d_in[1];
  const float* posE  = (const float*)d_in[2];
  const float* w_qkv = (const float*)d_in[3];
  const float* b_qkv = (const float*)d_in[4];
  const float* ln1g  = (const float*)d_in[5];
  const float* ln1b  = (const float*)d_in[6];
  const float* ln2g  = (const float*)d_in[7];
  const float* ln2b  = (const float*)d_in[8];
  const float* fw1   = (const float*)d_in[9];
  const float* fb1   = (const float*)d_in[10];
  const float* fw2   = (const float*)d_in[11];
  const float* fb2   = (const float*)d_in[12];
  const float* outw  = (const float*)d_in[13];
  const float* outb  = (const float*)d_in[14];
  float* out = (float*)d_out;

  const size_t NT = (size_t)BB * TS;  // 4096 tokens
  const size_t MB = 1024 * 1024;
  // Workspace: 32 MB total (proven safe round 2).
  //   h_bf  [0, 8M):  bf16 residual stream [4096, 1024]
  //   S = [8M, 32M) 24 MB, time-shared:
  //     attn phase (per 2-batch group): a_bf [0,4M) | qkv_bf [4M,16M)
  //     ff phase: a2_bf [0,8M) pristine LN2 | f1_bf [8M,24M) (slab 2048)
  bf16_t* h_bf = (bf16_t*)d_ws;
  char*   S    = (char*)d_ws + 8 * MB;
  bf16_t* a_bf   = (bf16_t*)S;
  bf16_t* qkv_bf = (bf16_t*)(S + 4 * MB);
  bf16_t* a2_bf  = (bf16_t*)S;
  bf16_t* f1_bf  = (bf16_t*)(S + 8 * MB);

  k_embed<<<(NT * DM) / 1024, 256, 0, stream>>>(x, tokE, posE, h_bf);
  for (int l = 0; l < NLY; l++) {
    // --- attention, 2-batch groups (M=2048 QKV GEMM, grid 384) ---
    for (int g = 0; g < 2; g++) {
      bf16_t* hg = h_bf + (size_t)g * 2 * TS * DM;
      k_ln<<<2 * TS / 4, 256, 0, stream>>>(hg, ln1g + l * DM, ln1b + l * DM,
                                           a_bf, nullptr);
      k_gemm<false, false><<<dim3(3 * DM / 128, 2 * TS / 128), 256, 0, stream>>>(
          a_bf, w_qkv + (size_t)l * 3 * DM * DM, b_qkv + l * 3 * DM, qkv_bf,
          2 * TS, 3 * DM, DM, DM);
      k_flash<<<dim3(NHD, TS / 64, 2), 256, 0, stream>>>(qkv_bf, hg);
    }
    // --- ln2: in-place into h_bf (residual basis) + pristine copy a2_bf ---
    k_ln<<<NT / 4, 256, 0, stream>>>(h_bf, ln2g + l * DM, ln2b + l * DM,
                                     h_bf, a2_bf);
    // --- FF: 2 slabs of 2048 over DFF; FF1 reads pristine a2_bf,
    //     FF2 accumulates into h_bf (bias on slab 0 only) ---
    for (int s = 0; s < 2; s++) {
      k_gemm<true, false><<<dim3(2048 / 128, NT / 128), 256, 0, stream>>>(
          a2_bf, fw1 + (size_t)l * DFF * DM + (size_t)s * 2048 * DM,
          fb1 + l * DFF + s * 2048, f1_bf, NT, 2048, DM, DM);
      k_gemm<false, true><<<dim3(DM / 128, NT / 128), 256, 0, stream>>>(
          f1_bf, fw2 + (size_t)l * DM * DFF + s * 2048,
          s == 0 ? fb2 + l * DM : nullptr, h_bf, NT, DM, 2048, DFF);
    }
  }
  k_logits<<<NT / 4, 256, 0, stream>>>(h_bf, outw, outb, out);
}